// Round 4
// baseline (401.216 us; speedup 1.0000x reference)
//
#include <hip/hip_runtime.h>
#include <hip/hip_bf16.h>
#include <math.h>

// ws layout (floats): [0,32768) feat512; [33792,33856) qacc; word 33856 = grid-barrier ctr
// Wh f16 [512][64] at byte offset 1MB
// f16x2 state ping-pong at byte offset 4MB: SA, SB (each 64*65536*4B = 16.78MB)

typedef _Float16 h4 __attribute__((ext_vector_type(4)));
typedef _Float16 h8 __attribute__((ext_vector_type(8)));
typedef float f32x4 __attribute__((ext_vector_type(4)));

__device__ __forceinline__ float2 cmulf(float2 a, float2 b){
    return make_float2(a.x*b.x - a.y*b.y, a.x*b.y + a.y*b.x);
}
__device__ __forceinline__ void cswap(float2& a, float2& b){ float2 t=a; a=b; b=t; }
__device__ __forceinline__ unsigned packh2(float2 a){
    union{ _Float16 h[2]; unsigned u; } z;
    z.h[0] = (_Float16)a.x; z.h[1] = (_Float16)a.y; return z.u;
}
__device__ __forceinline__ float2 unpackh2(unsigned u){
    union{ unsigned u; _Float16 h[2]; } z; z.u = u;
    return make_float2((float)z.h[0], (float)z.h[1]);
}

// ---------------- init: zero feat/qacc/ctr + W f32->f16 (K 48->64 zero-pad) ----------------
__global__ void k_init0(const float* __restrict__ Wc, _Float16* __restrict__ Wh,
                        float* __restrict__ ws){
    int i = blockIdx.x*256 + threadIdx.x;   // 32768 threads
    ws[i] = 0.0f;                           // feat
    int ch = i >> 6, k = i & 63;
    Wh[i] = (k < 48) ? (_Float16)Wc[ch*48 + k] : (_Float16)0.f;
    if (i < 64) ws[33792 + i] = 0.0f;       // qacc
    if (i == 0) ((unsigned*)ws)[33856] = 0u;// barrier ctr
}

// ---------------- conv + relu + global-avg-pool via MFMA ----------------
__global__ __launch_bounds__(512) void k_conv_mfma(const float* __restrict__ x,
            const _Float16* __restrict__ Wh, const float* __restrict__ bc,
            float* __restrict__ feat){
    extern __shared__ _Float16 Al[];   // [224][72]
    const int tid = threadIdx.x;
    const int b = blockIdx.x / 14, seg = blockIdx.x % 14;
    for (int idx = tid; idx < 2688; idx += 512){
        int cr = idx / 224, p = idx - cr*224;
        int cc = cr >> 2, r = cr & 3;
        int ro = p / 56, ow = p - ro*56;
        int ih = (seg*4 + ro)*4 + r;
        float4 v = *(const float4*)&x[(((size_t)b*3 + cc)*224 + ih)*224 + ow*4];
        h4 hv; hv[0]=(_Float16)v.x; hv[1]=(_Float16)v.y; hv[2]=(_Float16)v.z; hv[3]=(_Float16)v.w;
        *(h4*)&Al[p*72 + cr*4] = hv;
    }
    for (int idx = tid; idx < 896; idx += 512){
        int p = idx >> 2, j = idx & 3;
        *(h4*)&Al[p*72 + 48 + j*4] = (h4){0,0,0,0};
    }
    __syncthreads();
    const int wv = tid >> 6, lane = tid & 63;
    const int col = lane & 15, kg = lane >> 4;
    const int n0 = wv * 64;
    h8 Bf[4], Bf2[4];
    float bias[4], pool[4];
    #pragma unroll
    for (int nt=0; nt<4; ++nt){
        int ch = n0 + nt*16 + col;
        Bf[nt]  = *(const h8*)&Wh[ch*64 + kg*8];
        Bf2[nt] = *(const h8*)&Wh[ch*64 + 32 + kg*8];
        bias[nt] = bc[ch];
        pool[nt] = 0.f;
    }
    #pragma unroll 2
    for (int mt=0; mt<14; ++mt){
        const _Float16* ar = &Al[(mt*16 + col)*72];
        h8 Af  = *(const h8*)&ar[kg*8];
        h8 Af2 = *(const h8*)&ar[32 + kg*8];
        #pragma unroll
        for (int nt=0; nt<4; ++nt){
            f32x4 acc = {0.f,0.f,0.f,0.f};
            acc = __builtin_amdgcn_mfma_f32_16x16x32_f16(Af,  Bf[nt],  acc, 0,0,0);
            acc = __builtin_amdgcn_mfma_f32_16x16x32_f16(Af2, Bf2[nt], acc, 0,0,0);
            #pragma unroll
            for (int j=0;j<4;++j) pool[nt] += fmaxf(acc[j] + bias[nt], 0.f);
        }
    }
    #pragma unroll
    for (int nt=0; nt<4; ++nt){
        pool[nt] += __shfl_xor(pool[nt], 16);
        pool[nt] += __shfl_xor(pool[nt], 32);
    }
    if (lane < 16){
        #pragma unroll
        for (int nt=0; nt<4; ++nt)
            atomicAdd(&feat[b*512 + n0 + nt*16 + lane], pool[nt]);
    }
}

// ---------------- fused VQC: reducer + 5 layers + measure + sigmoid ----------------
// index i[15:0], wire w <-> bit 15-w. chunk c = i[15:14]; m = i[13:0].
// Rounds per layer: R1 regs {m13,m12,m1,m0} (w2,3,14,15), R2 {m11..m8} (w4..7),
// R3 {m7..m4} (w8..11), R4 {m3..m0} (w12..15). LDS packed f16x2 per amp.
__device__ __forceinline__ int SWZ(int m){ return m ^ ((m>>5)&31); }

template<int M>
__device__ __forceinline__ void applyw(float2* amp, const float* gw){
    float c_ = gw[0], s_ = gw[1], cp_ = gw[2], sp_ = gw[3];
    #pragma unroll
    for (int v=0; v<16; ++v) if (!(v & M)){
        float2 a0 = amp[v], a1 = amp[v|M];
        float n0x = c_*a0.x - s_*a1.x, n0y = c_*a0.y - s_*a1.y;
        float n1x = s_*a0.x + c_*a1.x, n1y = s_*a0.y + c_*a1.y;
        amp[v]   = make_float2(n0x, n0y);
        amp[v|M] = make_float2(n1x*cp_ - n1y*sp_, n1x*sp_ + n1y*cp_);
    }
}
__device__ __forceinline__ void chain3(float2* amp){
    cswap(amp[8],amp[12]); cswap(amp[9],amp[13]); cswap(amp[10],amp[14]); cswap(amp[11],amp[15]);
    cswap(amp[4],amp[6]);  cswap(amp[5],amp[7]);  cswap(amp[12],amp[14]); cswap(amp[13],amp[15]);
    cswap(amp[2],amp[3]);  cswap(amp[6],amp[7]);  cswap(amp[10],amp[11]); cswap(amp[14],amp[15]);
}
__device__ __forceinline__ void swap8u(float2* amp){
    #pragma unroll
    for (int v=0; v<8; ++v) cswap(amp[v], amp[v+8]);
}

__device__ __forceinline__ void gridbar(unsigned* ctr, unsigned target){
    __syncthreads();
    if (threadIdx.x == 0){
        __threadfence();
        __hip_atomic_fetch_add(ctr, 1u, __ATOMIC_ACQ_REL, __HIP_MEMORY_SCOPE_AGENT);
        while (__hip_atomic_load(ctr, __ATOMIC_ACQUIRE, __HIP_MEMORY_SCOPE_AGENT) < target){
            __builtin_amdgcn_s_sleep(2);
        }
    }
    __syncthreads();
}

__global__ __launch_bounds__(1024) void k_vqc_all(
        const float* __restrict__ wgt,      // [6][16][2]
        const float* __restrict__ feat,     // [64][512]
        const float* __restrict__ Wr, const float* __restrict__ br,
        unsigned* __restrict__ SA, unsigned* __restrict__ SB,
        float* __restrict__ qacc, unsigned* __restrict__ ctr,
        float* __restrict__ out){
    extern __shared__ char smem[];
    unsigned* pk     = (unsigned*)smem;            // [16384] f16x2 amps
    float*    gatesA = (float*)(smem + 65536);     // [6][16][4]
    float2*   Atab   = (float2*)(smem + 67072);    // [256]
    float2*   Btab   = (float2*)(smem + 69120);    // [256]
    float*    angL   = (float*)(smem + 71168);     // [16]
    const int T = threadIdx.x;
    const int c = blockIdx.x >> 6;     // chunk
    const int b = blockIdx.x & 63;     // sample

    // ---- reducer: angles for sample b (all 16 waves) ----
    {
        int w = T >> 6, l = T & 63;
        float acc = 0.f;
        #pragma unroll
        for (int k=0;k<8;++k){
            int idx = l + 64*k;
            acc += (feat[b*512 + idx] * (1.0f/3136.0f)) * Wr[w*512 + idx];
        }
        #pragma unroll
        for (int m=32;m>=1;m>>=1) acc += __shfl_xor(acc, m);
        if (l == 0) angL[w] = tanhf(acc + br[w]) * 3.14159265358979323846f;
    }
    __syncthreads();

    // ---- product-state tables (layer0 + encoding, Gray map) + all-layer gates ----
    if (T < 256){
        int h = T, g = h ^ (h>>1);
        float2 p = make_float2(1.f, 0.f);
        #pragma unroll
        for (int w=0; w<8; ++w){
            float th = wgt[w*2+0], ph = wgt[w*2+1];
            float a  = angL[w];
            float sb, cb; sincosf(0.5f*(a+th), &sb, &cb);
            float sp, cp; sincosf(ph, &sp, &cp);
            if ((g >> (7-w)) & 1) p = cmulf(p, make_float2(sb*cp, sb*sp));
            else { p.x *= cb; p.y *= cb; }
        }
        Atab[h] = p;
    } else if (T < 512){
        int l8 = T - 256, gl = (l8 ^ (l8>>1)) & 255;
        float2 p = make_float2(1.f, 0.f);
        #pragma unroll
        for (int w=8; w<16; ++w){
            float th = wgt[w*2+0], ph = wgt[w*2+1];
            float a  = angL[w];
            float sb, cb; sincosf(0.5f*(a+th), &sb, &cb);
            float sp, cp; sincosf(ph, &sp, &cp);
            if ((gl >> (15-w)) & 1) p = cmulf(p, make_float2(sb*cp, sb*sp));
            else { p.x *= cb; p.y *= cb; }
        }
        Btab[l8] = p;
    } else if (T < 608){
        int idx = T - 512;           // L*16+w for L=0..5
        float th = wgt[idx*2+0], ph = wgt[idx*2+1];
        float s_, c_, sp_, cp_;
        sincosf(0.5f*th, &s_, &c_);
        sincosf(ph, &sp_, &cp_);
        gatesA[idx*4+0] = c_; gatesA[idx*4+1] = s_;
        gatesA[idx*4+2] = cp_; gatesA[idx*4+3] = sp_;
    }
    __syncthreads();

    for (int L=1; L<=5; ++L){
        const float* gL = gatesA + L*64;
        // G4 row for chunk c: wires 0,1 RY*RZ + CNOT(0,1)
        float2 G4r[4];
        {
            float c0_=gL[0], s0_=gL[1], cp0=gL[2], sp0=gL[3];
            float c1_=gL[4], s1_=gL[5], cp1=gL[6], sp1=gL[7];
            float2 U0[2][2] = {{{c0_,0.f},{-s0_,0.f}},{{s0_*cp0,s0_*sp0},{c0_*cp0,c0_*sp0}}};
            float2 U1[2][2] = {{{c1_,0.f},{-s1_,0.f}},{{s1_*cp1,s1_*sp1},{c1_*cp1,c1_*sp1}}};
            int c1b = c>>1, c0b = c&1;
            #pragma unroll
            for (int cp=0; cp<4; ++cp)
                G4r[cp] = cmulf(U0[c1b][cp>>1], U1[c0b ^ c1b][cp & 1]);
        }

        float2 amp[16];   // amp[(v2<<2)|u]: i = (c<<14)|(v2<<12)|(T<<2)|u
        if (L == 1){
            float2 Bt[4];
            #pragma unroll
            for (int u=0;u<4;++u) Bt[u] = Btab[((T&63)<<2)|u];
            #pragma unroll
            for (int v2=0; v2<4; ++v2){
                int ihi = (v2<<4) | ((T>>6)&15);
                float2 a[4] = {{0,0},{0,0},{0,0},{0,0}};
                #pragma unroll
                for (int cp=0; cp<4; ++cp){
                    float2 Ag = cmulf(G4r[cp], Atab[(cp<<6)|ihi]);
                    #pragma unroll
                    for (int u=0;u<4;++u){
                        float2 t = cmulf(Ag, Bt[u]);
                        a[u].x += t.x; a[u].y += t.y;
                    }
                }
                #pragma unroll
                for (int u=0;u<4;++u) amp[(v2<<2)|u] = a[u];
            }
        } else {
            const unsigned* base = ((L & 1) ? SB : SA) + ((size_t)b << 16);
            #pragma unroll
            for (int v2=0; v2<4; ++v2){
                float2 a[4] = {{0,0},{0,0},{0,0},{0,0}};
                #pragma unroll
                for (int cp=0; cp<4; ++cp){
                    uint4 q = *(const uint4*)(base + ((cp<<14)|(v2<<12)|(T<<2)));
                    float2 g = G4r[cp];
                    float2 t0=unpackh2(q.x), t1=unpackh2(q.y), t2=unpackh2(q.z), t3=unpackh2(q.w);
                    a[0].x += g.x*t0.x - g.y*t0.y; a[0].y += g.x*t0.y + g.y*t0.x;
                    a[1].x += g.x*t1.x - g.y*t1.y; a[1].y += g.x*t1.y + g.y*t1.x;
                    a[2].x += g.x*t2.x - g.y*t2.y; a[2].y += g.x*t2.y + g.y*t2.x;
                    a[3].x += g.x*t3.x - g.y*t3.y; a[3].y += g.x*t3.y + g.y*t3.x;
                }
                #pragma unroll
                for (int u=0;u<4;++u) amp[(v2<<2)|u] = a[u];
            }
        }
        // R1: wires 2(b3),3(b2),14(b1),15(b0)
        applyw<8>(amp, gL+2*4);
        applyw<4>(amp, gL+3*4);
        applyw<2>(amp, gL+14*4);
        applyw<1>(amp, gL+15*4);
        if (c & 1) swap8u(amp);      // CN(1,2)
        cswap(amp[8],amp[12]); cswap(amp[9],amp[13]); cswap(amp[10],amp[14]); cswap(amp[11],amp[15]); // CN(2,3)
        #pragma unroll
        for (int r=0;r<16;++r)
            pk[SWZ(((r>>2)<<12) | (T<<2) | (r&3))] = packh2(amp[r]);
        __syncthreads();
        // R2: wires 4..7 (m11..m8)
        {
            int hi = (T>>8)<<12, lo = T & 255;
            #pragma unroll
            for (int r=0;r<16;++r) amp[r] = unpackh2(pk[SWZ(hi | (r<<8) | lo)]);
            applyw<8>(amp, gL+4*4); applyw<4>(amp, gL+5*4);
            applyw<2>(amp, gL+6*4); applyw<1>(amp, gL+7*4);
            if ((T>>8)&1) swap8u(amp);   // CN(3,4)
            chain3(amp);                 // CN(4,5),(5,6),(6,7)
            __syncthreads();
            #pragma unroll
            for (int r=0;r<16;++r) pk[SWZ(hi | (r<<8) | lo)] = packh2(amp[r]);
        }
        __syncthreads();
        // R3: wires 8..11 (m7..m4)
        {
            int hi = (T>>4)<<8, lo = T & 15;
            #pragma unroll
            for (int r=0;r<16;++r) amp[r] = unpackh2(pk[SWZ(hi | (r<<4) | lo)]);
            applyw<8>(amp, gL+8*4);  applyw<4>(amp, gL+9*4);
            applyw<2>(amp, gL+10*4); applyw<1>(amp, gL+11*4);
            if ((T>>4)&1) swap8u(amp);   // CN(7,8)
            chain3(amp);                 // CN(8,9),(9,10),(10,11)
            __syncthreads();
            #pragma unroll
            for (int r=0;r<16;++r) pk[SWZ(hi | (r<<4) | lo)] = packh2(amp[r]);
        }
        __syncthreads();
        // R4: wires 12..15 (m3..m0)
        {
            #pragma unroll
            for (int r=0;r<16;++r) amp[r] = unpackh2(pk[SWZ((T<<4) | r)]);
            applyw<8>(amp, gL+12*4); applyw<4>(amp, gL+13*4);
            if (T & 1) swap8u(amp);      // CN(11,12)
            chain3(amp);                 // CN(12,13),(13,14),(14,15)
            if (L < 5){
                unsigned* po = ((L & 1) ? SA : SB) + (((size_t)b<<16) | (c<<14) | (T<<4));
                #pragma unroll
                for (int k2=0;k2<4;++k2){
                    uint4 qq;
                    qq.x = packh2(amp[k2*4+0]); qq.y = packh2(amp[k2*4+1]);
                    qq.z = packh2(amp[k2*4+2]); qq.w = packh2(amp[k2*4+3]);
                    *(uint4*)(po + k2*4) = qq;
                }
                gridbar(ctr, 256u * (unsigned)L);
            } else {
                float ps = 0.f;
                #pragma unroll
                for (int r=0;r<16;++r) ps += amp[r].x*amp[r].x + amp[r].y*amp[r].y;
                #pragma unroll
                for (int m=32;m>=1;m>>=1) ps += __shfl_xor(ps, m);
                float* red16 = (float*)Atab;     // tabs dead after L=1
                __syncthreads();
                if ((T & 63) == 0) red16[T>>6] = ps;
                __syncthreads();
                if (T == 0){
                    float tot = 0.f;
                    #pragma unroll
                    for (int k=0;k<16;++k) tot += red16[k];
                    float sgn = (c & 2) ? -1.f : 1.f;   // wire0 = c bit1
                    atomicAdd(&qacc[b], sgn*tot);
                }
                gridbar(ctr, 256u * 5u);
                if (blockIdx.x == 0 && T < 64){
                    float q = __hip_atomic_load(&qacc[T], __ATOMIC_ACQUIRE, __HIP_MEMORY_SCOPE_AGENT);
                    out[T] = 1.f/(1.f + expf(-q));
                }
            }
        }
    }
}

extern "C" void kernel_launch(void* const* d_in, const int* in_sizes, int n_in,
                              void* d_out, int out_size, void* d_ws, size_t ws_size,
                              hipStream_t stream){
    (void)in_sizes; (void)n_in; (void)out_size; (void)ws_size;
    const float* x  = (const float*)d_in[0];
    const float* Wc = (const float*)d_in[1];
    const float* bc = (const float*)d_in[2];
    const float* Wr = (const float*)d_in[3];
    const float* br = (const float*)d_in[4];
    const float* wq = (const float*)d_in[5];
    float* ws     = (float*)d_ws;
    float* feat   = ws;
    float* qacc   = ws + 33792;
    unsigned* ctr = (unsigned*)ws + 33856;
    _Float16* Wh = (_Float16*)((char*)d_ws + ((size_t)1<<20));
    unsigned* SA = (unsigned*)((char*)d_ws + ((size_t)4<<20));
    unsigned* SB = SA + ((size_t)64<<16);
    float* outF = (float*)d_out;

    const int dynC = 224*72*2;           // 32256 B
    const int dynV = 71232;              // pk+gates+tabs+ang
    hipFuncSetAttribute(reinterpret_cast<const void*>(&k_conv_mfma),
                        hipFuncAttributeMaxDynamicSharedMemorySize, dynC);
    hipFuncSetAttribute(reinterpret_cast<const void*>(&k_vqc_all),
                        hipFuncAttributeMaxDynamicSharedMemorySize, dynV);

    k_init0<<<128,256,0,stream>>>(Wc, Wh, ws);
    k_conv_mfma<<<64*14,512,dynC,stream>>>(x, Wh, bc, feat);
    k_vqc_all<<<256,1024,dynV,stream>>>(wq, feat, Wr, br, SA, SB, qacc, ctr, outF);
}

// Round 5
// 248.333 us; speedup vs baseline: 1.6156x; 1.6156x over previous
//
#include <hip/hip_runtime.h>
#include <hip/hip_bf16.h>
#include <math.h>

// ws layout (floats): [0,32768) feat512; [33792,33856) qacc; [33856,33920) fincnt(u32);
//                     [33920,35968) quartet barrier ctrs (u32, 128B spacing)
// Wh f16 [512][64] at byte offset 1MB
// f16x2 state ping-pong at byte offset 4MB: SA, SB (each 64*65536*4B = 16.78MB)

typedef _Float16 h4 __attribute__((ext_vector_type(4)));
typedef _Float16 h8 __attribute__((ext_vector_type(8)));
typedef float f32x4 __attribute__((ext_vector_type(4)));

__device__ __forceinline__ float2 cmulf(float2 a, float2 b){
    return make_float2(a.x*b.x - a.y*b.y, a.x*b.y + a.y*b.x);
}
__device__ __forceinline__ void cswap(float2& a, float2& b){ float2 t=a; a=b; b=t; }
__device__ __forceinline__ unsigned packh2(float2 a){
    union{ _Float16 h[2]; unsigned u; } z;
    z.h[0] = (_Float16)a.x; z.h[1] = (_Float16)a.y; return z.u;
}
__device__ __forceinline__ float2 unpackh2(unsigned u){
    union{ unsigned u; _Float16 h[2]; } z; z.u = u;
    return make_float2((float)z.h[0], (float)z.h[1]);
}

// ---------------- init: zero feat/qacc/cnt/bars + W f32->f16 (K 48->64 zero-pad) ----------------
__global__ void k_init0(const float* __restrict__ Wc, _Float16* __restrict__ Wh,
                        float* __restrict__ ws){
    int i = blockIdx.x*256 + threadIdx.x;   // 32768 threads
    ws[i] = 0.0f;                           // feat
    int ch = i >> 6, k = i & 63;
    Wh[i] = (k < 48) ? (_Float16)Wc[ch*48 + k] : (_Float16)0.f;
    if (i < 2176) ws[33792 + i] = 0.0f;     // qacc + fincnt + barriers
}

// ---------------- conv + relu + global-avg-pool via MFMA ----------------
__global__ __launch_bounds__(512) void k_conv_mfma(const float* __restrict__ x,
            const _Float16* __restrict__ Wh, const float* __restrict__ bc,
            float* __restrict__ feat){
    extern __shared__ _Float16 Al[];   // [224][72]
    const int tid = threadIdx.x;
    const int b = blockIdx.x / 14, seg = blockIdx.x % 14;
    for (int idx = tid; idx < 2688; idx += 512){
        int cr = idx / 224, p = idx - cr*224;
        int cc = cr >> 2, r = cr & 3;
        int ro = p / 56, ow = p - ro*56;
        int ih = (seg*4 + ro)*4 + r;
        float4 v = *(const float4*)&x[(((size_t)b*3 + cc)*224 + ih)*224 + ow*4];
        h4 hv; hv[0]=(_Float16)v.x; hv[1]=(_Float16)v.y; hv[2]=(_Float16)v.z; hv[3]=(_Float16)v.w;
        *(h4*)&Al[p*72 + cr*4] = hv;
    }
    for (int idx = tid; idx < 896; idx += 512){
        int p = idx >> 2, j = idx & 3;
        *(h4*)&Al[p*72 + 48 + j*4] = (h4){0,0,0,0};
    }
    __syncthreads();
    const int wv = tid >> 6, lane = tid & 63;
    const int col = lane & 15, kg = lane >> 4;
    const int n0 = wv * 64;
    h8 Bf[4], Bf2[4];
    float bias[4], pool[4];
    #pragma unroll
    for (int nt=0; nt<4; ++nt){
        int ch = n0 + nt*16 + col;
        Bf[nt]  = *(const h8*)&Wh[ch*64 + kg*8];
        Bf2[nt] = *(const h8*)&Wh[ch*64 + 32 + kg*8];
        bias[nt] = bc[ch];
        pool[nt] = 0.f;
    }
    #pragma unroll 2
    for (int mt=0; mt<14; ++mt){
        const _Float16* ar = &Al[(mt*16 + col)*72];
        h8 Af  = *(const h8*)&ar[kg*8];
        h8 Af2 = *(const h8*)&ar[32 + kg*8];
        #pragma unroll
        for (int nt=0; nt<4; ++nt){
            f32x4 acc = {0.f,0.f,0.f,0.f};
            acc = __builtin_amdgcn_mfma_f32_16x16x32_f16(Af,  Bf[nt],  acc, 0,0,0);
            acc = __builtin_amdgcn_mfma_f32_16x16x32_f16(Af2, Bf2[nt], acc, 0,0,0);
            #pragma unroll
            for (int j=0;j<4;++j) pool[nt] += fmaxf(acc[j] + bias[nt], 0.f);
        }
    }
    #pragma unroll
    for (int nt=0; nt<4; ++nt){
        pool[nt] += __shfl_xor(pool[nt], 16);
        pool[nt] += __shfl_xor(pool[nt], 32);
    }
    if (lane < 16){
        #pragma unroll
        for (int nt=0; nt<4; ++nt)
            atomicAdd(&feat[b*512 + n0 + nt*16 + lane], pool[nt]);
    }
}

// ---------------- fused VQC: reducer + 5 layers + measure + sigmoid ----------------
// index i[15:0], wire w <-> bit 15-w. chunk c = i[15:14]; m = i[13:0].
// Rounds per layer: R1 regs {m13,m12,m1,m0} (w2,3,14,15), R2 {m11..m8} (w4..7),
// R3 {m7..m4} (w8..11), R4 {m3..m0} (w12..15). LDS packed f16x2 per amp.
__device__ __forceinline__ int SWZ(int m){ return m ^ ((m>>5)&31); }

template<int M>
__device__ __forceinline__ void applyw(float2* amp, const float* gw){
    float c_ = gw[0], s_ = gw[1], cp_ = gw[2], sp_ = gw[3];
    #pragma unroll
    for (int v=0; v<16; ++v) if (!(v & M)){
        float2 a0 = amp[v], a1 = amp[v|M];
        float n0x = c_*a0.x - s_*a1.x, n0y = c_*a0.y - s_*a1.y;
        float n1x = s_*a0.x + c_*a1.x, n1y = s_*a0.y + c_*a1.y;
        amp[v]   = make_float2(n0x, n0y);
        amp[v|M] = make_float2(n1x*cp_ - n1y*sp_, n1x*sp_ + n1y*cp_);
    }
}
__device__ __forceinline__ void chain3(float2* amp){
    cswap(amp[8],amp[12]); cswap(amp[9],amp[13]); cswap(amp[10],amp[14]); cswap(amp[11],amp[15]);
    cswap(amp[4],amp[6]);  cswap(amp[5],amp[7]);  cswap(amp[12],amp[14]); cswap(amp[13],amp[15]);
    cswap(amp[2],amp[3]);  cswap(amp[6],amp[7]);  cswap(amp[10],amp[11]); cswap(amp[14],amp[15]);
}
__device__ __forceinline__ void swap8u(float2* amp){
    #pragma unroll
    for (int v=0; v<8; ++v) cswap(amp[v], amp[v+8]);
}

// quartet barrier: arrive RELEASE once, spin RELAXED (no cache maintenance),
// one ACQUIRE at exit (single L1/L2 inv — same price a kernel boundary pays).
__device__ __forceinline__ void qbar(unsigned* bar, unsigned target){
    __syncthreads();
    if (threadIdx.x == 0){
        __hip_atomic_fetch_add(bar, 1u, __ATOMIC_RELEASE, __HIP_MEMORY_SCOPE_AGENT);
        while (__hip_atomic_load(bar, __ATOMIC_RELAXED, __HIP_MEMORY_SCOPE_AGENT) < target)
            __builtin_amdgcn_s_sleep(16);
        (void)__hip_atomic_load(bar, __ATOMIC_ACQUIRE, __HIP_MEMORY_SCOPE_AGENT);
    }
    __syncthreads();
}

__global__ __launch_bounds__(1024) void k_vqc_all(
        const float* __restrict__ wgt,      // [6][16][2]
        const float* __restrict__ feat,     // [64][512]
        const float* __restrict__ Wr, const float* __restrict__ br,
        unsigned* __restrict__ SA, unsigned* __restrict__ SB,
        float* __restrict__ qacc, unsigned* __restrict__ fincnt,
        unsigned* __restrict__ barBase,
        float* __restrict__ out){
    extern __shared__ char smem[];
    unsigned* pk     = (unsigned*)smem;            // [16384] f16x2 amps
    float*    gatesA = (float*)(smem + 65536);     // [6][16][4]
    float2*   Atab   = (float2*)(smem + 67072);    // [256]
    float2*   Btab   = (float2*)(smem + 69120);    // [256]
    float*    angL   = (float*)(smem + 71168);     // [16]
    const int T = threadIdx.x;
    const int c = blockIdx.x >> 6;     // chunk
    const int b = blockIdx.x & 63;     // sample
    unsigned* bar = barBase + b*32;    // 128B-spaced per-sample ctr

    // ---- reducer: angles for sample b (all 16 waves) ----
    {
        int w = T >> 6, l = T & 63;
        float acc = 0.f;
        #pragma unroll
        for (int k=0;k<8;++k){
            int idx = l + 64*k;
            acc += (feat[b*512 + idx] * (1.0f/3136.0f)) * Wr[w*512 + idx];
        }
        #pragma unroll
        for (int m=32;m>=1;m>>=1) acc += __shfl_xor(acc, m);
        if (l == 0) angL[w] = tanhf(acc + br[w]) * 3.14159265358979323846f;
    }
    __syncthreads();

    // ---- product-state tables (layer0 + encoding, Gray map) + all-layer gates ----
    if (T < 256){
        int h = T, g = h ^ (h>>1);
        float2 p = make_float2(1.f, 0.f);
        #pragma unroll
        for (int w=0; w<8; ++w){
            float th = wgt[w*2+0], ph = wgt[w*2+1];
            float a  = angL[w];
            float sb, cb; sincosf(0.5f*(a+th), &sb, &cb);
            float sp, cp; sincosf(ph, &sp, &cp);
            if ((g >> (7-w)) & 1) p = cmulf(p, make_float2(sb*cp, sb*sp));
            else { p.x *= cb; p.y *= cb; }
        }
        Atab[h] = p;
    } else if (T < 512){
        int l8 = T - 256, gl = (l8 ^ (l8>>1)) & 255;
        float2 p = make_float2(1.f, 0.f);
        #pragma unroll
        for (int w=8; w<16; ++w){
            float th = wgt[w*2+0], ph = wgt[w*2+1];
            float a  = angL[w];
            float sb, cb; sincosf(0.5f*(a+th), &sb, &cb);
            float sp, cp; sincosf(ph, &sp, &cp);
            if ((gl >> (15-w)) & 1) p = cmulf(p, make_float2(sb*cp, sb*sp));
            else { p.x *= cb; p.y *= cb; }
        }
        Btab[l8] = p;
    } else if (T < 608){
        int idx = T - 512;           // L*16+w for L=0..5
        float th = wgt[idx*2+0], ph = wgt[idx*2+1];
        float s_, c_, sp_, cp_;
        sincosf(0.5f*th, &s_, &c_);
        sincosf(ph, &sp_, &cp_);
        gatesA[idx*4+0] = c_; gatesA[idx*4+1] = s_;
        gatesA[idx*4+2] = cp_; gatesA[idx*4+3] = sp_;
    }
    __syncthreads();

    for (int L=1; L<=5; ++L){
        const float* gL = gatesA + L*64;
        // G4 row for chunk c: wires 0,1 RY*RZ + CNOT(0,1)
        float2 G4r[4];
        {
            float c0_=gL[0], s0_=gL[1], cp0=gL[2], sp0=gL[3];
            float c1_=gL[4], s1_=gL[5], cp1=gL[6], sp1=gL[7];
            float2 U0[2][2] = {{{c0_,0.f},{-s0_,0.f}},{{s0_*cp0,s0_*sp0},{c0_*cp0,c0_*sp0}}};
            float2 U1[2][2] = {{{c1_,0.f},{-s1_,0.f}},{{s1_*cp1,s1_*sp1},{c1_*cp1,c1_*sp1}}};
            int c1b = c>>1, c0b = c&1;
            #pragma unroll
            for (int cp=0; cp<4; ++cp)
                G4r[cp] = cmulf(U0[c1b][cp>>1], U1[c0b ^ c1b][cp & 1]);
        }

        float2 amp[16];   // amp[(v2<<2)|u]: i = (c<<14)|(v2<<12)|(T<<2)|u
        if (L == 1){
            float2 Bt[4];
            #pragma unroll
            for (int u=0;u<4;++u) Bt[u] = Btab[((T&63)<<2)|u];
            #pragma unroll
            for (int v2=0; v2<4; ++v2){
                int ihi = (v2<<4) | ((T>>6)&15);
                float2 a[4] = {{0,0},{0,0},{0,0},{0,0}};
                #pragma unroll
                for (int cp=0; cp<4; ++cp){
                    float2 Ag = cmulf(G4r[cp], Atab[(cp<<6)|ihi]);
                    #pragma unroll
                    for (int u=0;u<4;++u){
                        float2 t = cmulf(Ag, Bt[u]);
                        a[u].x += t.x; a[u].y += t.y;
                    }
                }
                #pragma unroll
                for (int u=0;u<4;++u) amp[(v2<<2)|u] = a[u];
            }
        } else {
            const unsigned* base = ((L & 1) ? SB : SA) + ((size_t)b << 16);
            #pragma unroll
            for (int v2=0; v2<4; ++v2){
                float2 a[4] = {{0,0},{0,0},{0,0},{0,0}};
                #pragma unroll
                for (int cp=0; cp<4; ++cp){
                    uint4 q = *(const uint4*)(base + ((cp<<14)|(v2<<12)|(T<<2)));
                    float2 g = G4r[cp];
                    float2 t0=unpackh2(q.x), t1=unpackh2(q.y), t2=unpackh2(q.z), t3=unpackh2(q.w);
                    a[0].x += g.x*t0.x - g.y*t0.y; a[0].y += g.x*t0.y + g.y*t0.x;
                    a[1].x += g.x*t1.x - g.y*t1.y; a[1].y += g.x*t1.y + g.y*t1.x;
                    a[2].x += g.x*t2.x - g.y*t2.y; a[2].y += g.x*t2.y + g.y*t2.x;
                    a[3].x += g.x*t3.x - g.y*t3.y; a[3].y += g.x*t3.y + g.y*t3.x;
                }
                #pragma unroll
                for (int u=0;u<4;++u) amp[(v2<<2)|u] = a[u];
            }
        }
        // R1: wires 2(b3),3(b2),14(b1),15(b0)
        applyw<8>(amp, gL+2*4);
        applyw<4>(amp, gL+3*4);
        applyw<2>(amp, gL+14*4);
        applyw<1>(amp, gL+15*4);
        if (c & 1) swap8u(amp);      // CN(1,2)
        cswap(amp[8],amp[12]); cswap(amp[9],amp[13]); cswap(amp[10],amp[14]); cswap(amp[11],amp[15]); // CN(2,3)
        #pragma unroll
        for (int r=0;r<16;++r)
            pk[SWZ(((r>>2)<<12) | (T<<2) | (r&3))] = packh2(amp[r]);
        __syncthreads();
        // R2: wires 4..7 (m11..m8)
        {
            int hi = (T>>8)<<12, lo = T & 255;
            #pragma unroll
            for (int r=0;r<16;++r) amp[r] = unpackh2(pk[SWZ(hi | (r<<8) | lo)]);
            applyw<8>(amp, gL+4*4); applyw<4>(amp, gL+5*4);
            applyw<2>(amp, gL+6*4); applyw<1>(amp, gL+7*4);
            if ((T>>8)&1) swap8u(amp);   // CN(3,4)
            chain3(amp);                 // CN(4,5),(5,6),(6,7)
            __syncthreads();
            #pragma unroll
            for (int r=0;r<16;++r) pk[SWZ(hi | (r<<8) | lo)] = packh2(amp[r]);
        }
        __syncthreads();
        // R3: wires 8..11 (m7..m4)
        {
            int hi = (T>>4)<<8, lo = T & 15;
            #pragma unroll
            for (int r=0;r<16;++r) amp[r] = unpackh2(pk[SWZ(hi | (r<<4) | lo)]);
            applyw<8>(amp, gL+8*4);  applyw<4>(amp, gL+9*4);
            applyw<2>(amp, gL+10*4); applyw<1>(amp, gL+11*4);
            if ((T>>4)&1) swap8u(amp);   // CN(7,8)
            chain3(amp);                 // CN(8,9),(9,10),(10,11)
            __syncthreads();
            #pragma unroll
            for (int r=0;r<16;++r) pk[SWZ(hi | (r<<4) | lo)] = packh2(amp[r]);
        }
        __syncthreads();
        // R4: wires 12..15 (m3..m0)
        {
            #pragma unroll
            for (int r=0;r<16;++r) amp[r] = unpackh2(pk[SWZ((T<<4) | r)]);
            applyw<8>(amp, gL+12*4); applyw<4>(amp, gL+13*4);
            if (T & 1) swap8u(amp);      // CN(11,12)
            chain3(amp);                 // CN(12,13),(13,14),(14,15)
            if (L < 5){
                unsigned* po = ((L & 1) ? SA : SB) + (((size_t)b<<16) | (c<<14) | (T<<4));
                #pragma unroll
                for (int k2=0;k2<4;++k2){
                    uint4 qq;
                    qq.x = packh2(amp[k2*4+0]); qq.y = packh2(amp[k2*4+1]);
                    qq.z = packh2(amp[k2*4+2]); qq.w = packh2(amp[k2*4+3]);
                    *(uint4*)(po + k2*4) = qq;
                }
                qbar(bar, 4u * (unsigned)L);   // quartet barrier (4 blocks of sample b)
            } else {
                float ps = 0.f;
                #pragma unroll
                for (int r=0;r<16;++r) ps += amp[r].x*amp[r].x + amp[r].y*amp[r].y;
                #pragma unroll
                for (int m=32;m>=1;m>>=1) ps += __shfl_xor(ps, m);
                float* red16 = (float*)Atab;     // tabs dead after L=1
                __syncthreads();
                if ((T & 63) == 0) red16[T>>6] = ps;
                __syncthreads();
                if (T == 0){
                    float tot = 0.f;
                    #pragma unroll
                    for (int k=0;k<16;++k) tot += red16[k];
                    float sgn = (c & 2) ? -1.f : 1.f;   // wire0 = c bit1
                    atomicAdd(&qacc[b], sgn*tot);
                    // last-arrival of the quartet computes the sigmoid
                    unsigned old = __hip_atomic_fetch_add(&fincnt[b], 1u,
                                        __ATOMIC_ACQ_REL, __HIP_MEMORY_SCOPE_AGENT);
                    if (old == 3u){
                        float q = __hip_atomic_load(&qacc[b], __ATOMIC_RELAXED,
                                        __HIP_MEMORY_SCOPE_AGENT);
                        out[b] = 1.f/(1.f + expf(-q));
                    }
                }
            }
        }
    }
}

extern "C" void kernel_launch(void* const* d_in, const int* in_sizes, int n_in,
                              void* d_out, int out_size, void* d_ws, size_t ws_size,
                              hipStream_t stream){
    (void)in_sizes; (void)n_in; (void)out_size; (void)ws_size;
    const float* x  = (const float*)d_in[0];
    const float* Wc = (const float*)d_in[1];
    const float* bc = (const float*)d_in[2];
    const float* Wr = (const float*)d_in[3];
    const float* br = (const float*)d_in[4];
    const float* wq = (const float*)d_in[5];
    float* ws     = (float*)d_ws;
    float* feat   = ws;
    float* qacc   = ws + 33792;
    unsigned* fincnt = (unsigned*)(ws + 33856);
    unsigned* barBase = (unsigned*)(ws + 33920);
    _Float16* Wh = (_Float16*)((char*)d_ws + ((size_t)1<<20));
    unsigned* SA = (unsigned*)((char*)d_ws + ((size_t)4<<20));
    unsigned* SB = SA + ((size_t)64<<16);
    float* outF = (float*)d_out;

    const int dynC = 224*72*2;           // 32256 B
    const int dynV = 71232;              // pk+gates+tabs+ang
    hipFuncSetAttribute(reinterpret_cast<const void*>(&k_conv_mfma),
                        hipFuncAttributeMaxDynamicSharedMemorySize, dynC);
    hipFuncSetAttribute(reinterpret_cast<const void*>(&k_vqc_all),
                        hipFuncAttributeMaxDynamicSharedMemorySize, dynV);

    k_init0<<<128,256,0,stream>>>(Wc, Wh, ws);
    k_conv_mfma<<<64*14,512,dynC,stream>>>(x, Wh, bc, feat);
    k_vqc_all<<<256,1024,dynV,stream>>>(wq, feat, Wr, br, SA, SB, qacc, fincnt, barBase, outF);
}

// Round 7
// 133.761 us; speedup vs baseline: 2.9995x; 1.8565x over previous
//
#include <hip/hip_runtime.h>
#include <hip/hip_bf16.h>
#include <math.h>

// ws layout (floats): [0,32768) feat512; [33792,33856) qacc; [33856,33920) fincnt(u32)
// Wh f16 [512][64] at byte offset 1MB
// f16x2 state ping-pong at byte offset 4MB: SA, SB (each 64*65536*4B = 16.78MB)

typedef _Float16 h4 __attribute__((ext_vector_type(4)));
typedef _Float16 h8 __attribute__((ext_vector_type(8)));
typedef float f32x4 __attribute__((ext_vector_type(4)));
typedef float f2 __attribute__((ext_vector_type(2)));

__device__ __forceinline__ f2 mk2(float a, float b){ f2 r; r.x=a; r.y=b; return r; }
__device__ __forceinline__ f2 cmulf(f2 a, f2 b){
    return mk2(a.x*b.x - a.y*b.y, a.x*b.y + a.y*b.x);
}
// acc += g*q (complex), packed-f32 form
__device__ __forceinline__ f2 cfma2(f2 g, f2 q, f2 acc){
    f2 qs = __builtin_shufflevector(q, q, 1, 0);
    acc += mk2(g.x, g.x) * q;
    acc += mk2(-g.y, g.y) * qs;
    return acc;
}
__device__ __forceinline__ void cswap(f2& a, f2& b){ f2 t=a; a=b; b=t; }
__device__ __forceinline__ unsigned pk2(f2 a){
    union{ _Float16 h[2]; unsigned u; } z;
    z.h[0] = (_Float16)a.x; z.h[1] = (_Float16)a.y; return z.u;
}
__device__ __forceinline__ f2 up2(unsigned u){
    union{ unsigned u; _Float16 h[2]; } z; z.u = u;
    return mk2((float)z.h[0], (float)z.h[1]);
}

// ---------------- init: zero feat/qacc/fincnt + W f32->f16 (K 48->64 zero-pad) ----------------
__global__ void k_init0(const float* __restrict__ Wc, _Float16* __restrict__ Wh,
                        float* __restrict__ ws){
    int i = blockIdx.x*256 + threadIdx.x;   // 32768 threads
    ws[i] = 0.0f;                           // feat
    int ch = i >> 6, k = i & 63;
    Wh[i] = (k < 48) ? (_Float16)Wc[ch*48 + k] : (_Float16)0.f;
    if (i < 128) ws[33792 + i] = 0.0f;      // qacc + fincnt
}

// ---------------- conv + relu + global-avg-pool via MFMA ----------------
__global__ __launch_bounds__(512) void k_conv_mfma(const float* __restrict__ x,
            const _Float16* __restrict__ Wh, const float* __restrict__ bc,
            float* __restrict__ feat){
    extern __shared__ _Float16 Al[];   // [224][72]
    const int tid = threadIdx.x;
    const int b = blockIdx.x / 14, seg = blockIdx.x % 14;
    for (int idx = tid; idx < 2688; idx += 512){
        int cr = idx / 224, p = idx - cr*224;
        int cc = cr >> 2, r = cr & 3;
        int ro = p / 56, ow = p - ro*56;
        int ih = (seg*4 + ro)*4 + r;
        float4 v = *(const float4*)&x[(((size_t)b*3 + cc)*224 + ih)*224 + ow*4];
        h4 hv; hv[0]=(_Float16)v.x; hv[1]=(_Float16)v.y; hv[2]=(_Float16)v.z; hv[3]=(_Float16)v.w;
        *(h4*)&Al[p*72 + cr*4] = hv;
    }
    for (int idx = tid; idx < 896; idx += 512){
        int p = idx >> 2, j = idx & 3;
        *(h4*)&Al[p*72 + 48 + j*4] = (h4){0,0,0,0};
    }
    __syncthreads();
    const int wv = tid >> 6, lane = tid & 63;
    const int col = lane & 15, kg = lane >> 4;
    const int n0 = wv * 64;
    h8 Bf[4], Bf2[4];
    float bias[4], pool[4];
    #pragma unroll
    for (int nt=0; nt<4; ++nt){
        int ch = n0 + nt*16 + col;
        Bf[nt]  = *(const h8*)&Wh[ch*64 + kg*8];
        Bf2[nt] = *(const h8*)&Wh[ch*64 + 32 + kg*8];
        bias[nt] = bc[ch];
        pool[nt] = 0.f;
    }
    #pragma unroll 2
    for (int mt=0; mt<14; ++mt){
        const _Float16* ar = &Al[(mt*16 + col)*72];
        h8 Af  = *(const h8*)&ar[kg*8];
        h8 Af2 = *(const h8*)&ar[32 + kg*8];
        #pragma unroll
        for (int nt=0; nt<4; ++nt){
            f32x4 acc = {0.f,0.f,0.f,0.f};
            acc = __builtin_amdgcn_mfma_f32_16x16x32_f16(Af,  Bf[nt],  acc, 0,0,0);
            acc = __builtin_amdgcn_mfma_f32_16x16x32_f16(Af2, Bf2[nt], acc, 0,0,0);
            #pragma unroll
            for (int j=0;j<4;++j) pool[nt] += fmaxf(acc[j] + bias[nt], 0.f);
        }
    }
    #pragma unroll
    for (int nt=0; nt<4; ++nt){
        pool[nt] += __shfl_xor(pool[nt], 16);
        pool[nt] += __shfl_xor(pool[nt], 32);
    }
    if (lane < 16){
        #pragma unroll
        for (int nt=0; nt<4; ++nt)
            atomicAdd(&feat[b*512 + n0 + nt*16 + lane], pool[nt]);
    }
}

// ---------------- VQC layer kernels ----------------
// index i[15:0], wire w <-> bit 15-w. chunk c = i[15:14]; m = i[13:0].
// Rounds per layer: R1 regs {m13,m12,m1,m0} (w2,3,14,15), R2 {m11..m8} (w4..7),
// R3 {m7..m4} (w8..11), R4 {m3..m0} (w12..15). LDS = packed f16x2 per amp.
// Quad-preserving swizzle: keeps dword bits [1:0] -> b128-able, banks balanced.
__device__ __forceinline__ int SW(int a){
    int h = ((a>>5)&7) ^ ((a>>6)&4) ^ ((a>>8)&3);
    return a ^ (h<<2);
}

template<int M>
__device__ __forceinline__ void applyw(f2* amp, const float* gw){
    f2 vc  = mk2(gw[0], gw[0]), vs  = mk2(gw[1], gw[1]);
    f2 vcp = mk2(gw[2], gw[2]), vsp = mk2(-gw[3], gw[3]);
    #pragma unroll
    for (int v=0; v<16; ++v) if (!(v & M)){
        f2 a0 = amp[v], a1 = amp[v|M];
        f2 n0 = vc*a0 - vs*a1;
        f2 t  = vs*a0 + vc*a1;
        f2 ts = __builtin_shufflevector(t, t, 1, 0);
        amp[v]   = n0;
        amp[v|M] = vcp*t + vsp*ts;
    }
}
__device__ __forceinline__ void chain3(f2* amp){
    cswap(amp[8],amp[12]); cswap(amp[9],amp[13]); cswap(amp[10],amp[14]); cswap(amp[11],amp[15]);
    cswap(amp[4],amp[6]);  cswap(amp[5],amp[7]);  cswap(amp[12],amp[14]); cswap(amp[13],amp[15]);
    cswap(amp[2],amp[3]);  cswap(amp[6],amp[7]);  cswap(amp[10],amp[11]); cswap(amp[14],amp[15]);
}
__device__ __forceinline__ void swap8u(f2* amp){
    #pragma unroll
    for (int v=0; v<8; ++v) cswap(amp[v], amp[v+8]);
}

template<bool INIT, bool MEASURE>
__global__ __launch_bounds__(1024) void k_vqc(
        const float* __restrict__ wgt,      // [6][16][2]
        const float* __restrict__ feat,     // [64][512] (INIT)
        const float* __restrict__ Wr, const float* __restrict__ br,
        const unsigned* __restrict__ sin_,  // f16x2 per amp
        unsigned* __restrict__ sout,
        float* __restrict__ qacc, unsigned* __restrict__ fincnt,
        float* __restrict__ out, int L){
    extern __shared__ unsigned pk[];               // [16384] (INIT/mid only)
    __shared__ float gatesS[64];                   // this layer's 16x{c,s,cp,sp}
    __shared__ float angS[16];
    __shared__ float red16[16];
    f2* Atab = (f2*)(pk + 16384);                  // [256] (INIT only)
    f2* Btab = Atab + 256;                         // [256]
    const int T = threadIdx.x;
    const int c = blockIdx.x >> 6;     // chunk; blockIdx=c*64+b -> sample XCD-local
    const int b = blockIdx.x & 63;     // sample

    if (INIT){
        // reducer: angles for sample b (all 16 waves)
        int w = T >> 6, l = T & 63;
        float acc = 0.f;
        #pragma unroll
        for (int k=0;k<8;++k){
            int idx = l + 64*k;
            acc += (feat[b*512 + idx] * (1.0f/3136.0f)) * Wr[w*512 + idx];
        }
        #pragma unroll
        for (int m=32;m>=1;m>>=1) acc += __shfl_xor(acc, m);
        if (l == 0) angS[w] = tanhf(acc + br[w]) * 3.14159265358979323846f;
        __syncthreads();
        // product state after encoding RY + layer0 1q; layer0 CNOT chain = Gray map
        if (T < 256){
            int h = T, g = h ^ (h>>1);
            f2 p = mk2(1.f, 0.f);
            #pragma unroll
            for (int w2=0; w2<8; ++w2){
                float th = wgt[w2*2+0], ph = wgt[w2*2+1];
                float a  = angS[w2];
                float sb, cb; sincosf(0.5f*(a+th), &sb, &cb);
                float sp, cp; sincosf(ph, &sp, &cp);
                if ((g >> (7-w2)) & 1) p = cmulf(p, mk2(sb*cp, sb*sp));
                else { p.x *= cb; p.y *= cb; }
            }
            Atab[h] = p;
        } else if (T < 512){
            int l8 = T - 256, gl = (l8 ^ (l8>>1)) & 255;
            f2 p = mk2(1.f, 0.f);
            #pragma unroll
            for (int w2=8; w2<16; ++w2){
                float th = wgt[w2*2+0], ph = wgt[w2*2+1];
                float a  = angS[w2];
                float sb, cb; sincosf(0.5f*(a+th), &sb, &cb);
                float sp, cp; sincosf(ph, &sp, &cp);
                if ((gl >> (15-w2)) & 1) p = cmulf(p, mk2(sb*cp, sb*sp));
                else { p.x *= cb; p.y *= cb; }
            }
            Btab[l8] = p;
        } else if (T < 528){
            int idx = T - 512;
            float th = wgt[(L*16+idx)*2+0], ph = wgt[(L*16+idx)*2+1];
            float s_, c_, sp_, cp_;
            sincosf(0.5f*th, &s_, &c_); sincosf(ph, &sp_, &cp_);
            gatesS[idx*4+0]=c_; gatesS[idx*4+1]=s_; gatesS[idx*4+2]=cp_; gatesS[idx*4+3]=sp_;
        }
    } else {
        if (T < 16){
            float th = wgt[(L*16+T)*2+0], ph = wgt[(L*16+T)*2+1];
            float s_, c_, sp_, cp_;
            sincosf(0.5f*th, &s_, &c_); sincosf(ph, &sp_, &cp_);
            gatesS[T*4+0]=c_; gatesS[T*4+1]=s_; gatesS[T*4+2]=cp_; gatesS[T*4+3]=sp_;
        }
    }
    __syncthreads();

    // G4 row for chunk c: wires 0,1 RY*RZ + CNOT(0,1)
    f2 G4r[4];
    {
        float c0_=gatesS[0], s0_=gatesS[1], cp0=gatesS[2], sp0=gatesS[3];
        float c1_=gatesS[4], s1_=gatesS[5], cp1=gatesS[6], sp1=gatesS[7];
        f2 U0[2][2] = {{mk2(c0_,0.f),mk2(-s0_,0.f)},{mk2(s0_*cp0,s0_*sp0),mk2(c0_*cp0,c0_*sp0)}};
        f2 U1[2][2] = {{mk2(c1_,0.f),mk2(-s1_,0.f)},{mk2(s1_*cp1,s1_*sp1),mk2(c1_*cp1,c1_*sp1)}};
        int c1b = c>>1, c0b = c&1;
        #pragma unroll
        for (int cp=0; cp<4; ++cp)
            G4r[cp] = cmulf(U0[c1b][cp>>1], U1[c0b ^ c1b][cp & 1]);
    }

    if (MEASURE){
        // After the G4 mix, ALL remaining layer-L ops are norm-preserving within
        // this block (thread-local rotations + in-block CNOT permutations), so
        // sum |amp|^2 right here.
        const unsigned* base = sin_ + ((size_t)b << 16);
        f2 acc2 = mk2(0.f, 0.f);
        #pragma unroll
        for (int v2=0; v2<4; ++v2){
            f2 a[4] = {mk2(0,0),mk2(0,0),mk2(0,0),mk2(0,0)};
            #pragma unroll
            for (int cp=0; cp<4; ++cp){
                uint4 q = *(const uint4*)(base + ((cp<<14)|(v2<<12)|(T<<2)));
                a[0] = cfma2(G4r[cp], up2(q.x), a[0]);
                a[1] = cfma2(G4r[cp], up2(q.y), a[1]);
                a[2] = cfma2(G4r[cp], up2(q.z), a[2]);
                a[3] = cfma2(G4r[cp], up2(q.w), a[3]);
            }
            #pragma unroll
            for (int u=0;u<4;++u) acc2 += a[u]*a[u];
        }
        float ps = acc2.x + acc2.y;
        #pragma unroll
        for (int m=32;m>=1;m>>=1) ps += __shfl_xor(ps, m);
        if ((T & 63) == 0) red16[T>>6] = ps;
        __syncthreads();
        if (T == 0){
            float tot = 0.f;
            #pragma unroll
            for (int k=0;k<16;++k) tot += red16[k];
            float sgn = (c & 2) ? -1.f : 1.f;   // wire0 = c bit1
            atomicAdd(&qacc[b], sgn*tot);
            unsigned old = __hip_atomic_fetch_add(&fincnt[b], 1u,
                                __ATOMIC_ACQ_REL, __HIP_MEMORY_SCOPE_AGENT);
            if (old == 3u){
                float q = __hip_atomic_load(&qacc[b], __ATOMIC_ACQUIRE,
                                __HIP_MEMORY_SCOPE_AGENT);
                out[b] = 1.f/(1.f + expf(-q));
            }
        }
        return;
    }

    f2 amp[16];   // amp[(v2<<2)|u]: i = (c<<14)|(v2<<12)|(T<<2)|u
    if (INIT){
        f2 Bt[4];
        #pragma unroll
        for (int u=0;u<4;++u) Bt[u] = Btab[((T&63)<<2)|u];
        #pragma unroll
        for (int v2=0; v2<4; ++v2){
            int ihi = (v2<<4) | ((T>>6)&15);
            f2 a[4] = {mk2(0,0),mk2(0,0),mk2(0,0),mk2(0,0)};
            #pragma unroll
            for (int cp=0; cp<4; ++cp){
                f2 Ag = cmulf(G4r[cp], Atab[(cp<<6)|ihi]);
                #pragma unroll
                for (int u=0;u<4;++u) a[u] = cfma2(Ag, Bt[u], a[u]);
            }
            #pragma unroll
            for (int u=0;u<4;++u) amp[(v2<<2)|u] = a[u];
        }
    } else {
        const unsigned* base = sin_ + ((size_t)b << 16);
        #pragma unroll
        for (int v2=0; v2<4; ++v2){
            f2 a[4] = {mk2(0,0),mk2(0,0),mk2(0,0),mk2(0,0)};
            #pragma unroll
            for (int cp=0; cp<4; ++cp){
                uint4 q = *(const uint4*)(base + ((cp<<14)|(v2<<12)|(T<<2)));
                a[0] = cfma2(G4r[cp], up2(q.x), a[0]);
                a[1] = cfma2(G4r[cp], up2(q.y), a[1]);
                a[2] = cfma2(G4r[cp], up2(q.z), a[2]);
                a[3] = cfma2(G4r[cp], up2(q.w), a[3]);
            }
            #pragma unroll
            for (int u=0;u<4;++u) amp[(v2<<2)|u] = a[u];
        }
    }
    // R1 gates: wires 2(b3),3(b2),14(b1),15(b0); w14/15 hoisted (commute to CN(13,14))
    applyw<8>(amp, gatesS+2*4);
    applyw<4>(amp, gatesS+3*4);
    applyw<2>(amp, gatesS+14*4);
    applyw<1>(amp, gatesS+15*4);
    if (c & 1) swap8u(amp);      // CN(1,2)
    cswap(amp[8],amp[12]); cswap(amp[9],amp[13]); cswap(amp[10],amp[14]); cswap(amp[11],amp[15]); // CN(2,3)
    #pragma unroll
    for (int v2=0; v2<4; ++v2){
        uint4 qq;
        qq.x = pk2(amp[v2*4+0]); qq.y = pk2(amp[v2*4+1]);
        qq.z = pk2(amp[v2*4+2]); qq.w = pk2(amp[v2*4+3]);
        *(uint4*)&pk[SW((v2<<12)|(T<<2))] = qq;
    }
    __syncthreads();
    // R2: wires 4..7 (m11..m8)
    {
        int hi = (T>>8)<<12, lo = T & 255;
        #pragma unroll
        for (int r=0;r<16;++r) amp[r] = up2(pk[SW(hi | (r<<8) | lo)]);
        applyw<8>(amp, gatesS+4*4); applyw<4>(amp, gatesS+5*4);
        applyw<2>(amp, gatesS+6*4); applyw<1>(amp, gatesS+7*4);
        if ((T>>8)&1) swap8u(amp);   // CN(3,4)
        chain3(amp);                 // CN(4,5),(5,6),(6,7)
        #pragma unroll
        for (int r=0;r<16;++r) pk[SW(hi | (r<<8) | lo)] = pk2(amp[r]);
    }
    __syncthreads();
    // R3: wires 8..11 (m7..m4)
    {
        int hi = (T>>4)<<8, lo = T & 15;
        #pragma unroll
        for (int r=0;r<16;++r) amp[r] = up2(pk[SW(hi | (r<<4) | lo)]);
        applyw<8>(amp, gatesS+8*4);  applyw<4>(amp, gatesS+9*4);
        applyw<2>(amp, gatesS+10*4); applyw<1>(amp, gatesS+11*4);
        if ((T>>4)&1) swap8u(amp);   // CN(7,8)
        chain3(amp);                 // CN(8,9),(9,10),(10,11)
        #pragma unroll
        for (int r=0;r<16;++r) pk[SW(hi | (r<<4) | lo)] = pk2(amp[r]);
    }
    __syncthreads();
    // R4: wires 12..15 (m3..m0)
    {
        #pragma unroll
        for (int q=0;q<4;++q){
            uint4 qq = *(const uint4*)&pk[SW((T<<4)|(q<<2))];
            amp[q*4+0]=up2(qq.x); amp[q*4+1]=up2(qq.y);
            amp[q*4+2]=up2(qq.z); amp[q*4+3]=up2(qq.w);
        }
        applyw<8>(amp, gatesS+12*4); applyw<4>(amp, gatesS+13*4);
        if (T & 1) swap8u(amp);      // CN(11,12)
        chain3(amp);                 // CN(12,13),(13,14),(14,15)
        unsigned* po = sout + (((size_t)b<<16) | (c<<14) | (T<<4));
        #pragma unroll
        for (int k2=0;k2<4;++k2){
            uint4 qq;
            qq.x = pk2(amp[k2*4+0]); qq.y = pk2(amp[k2*4+1]);
            qq.z = pk2(amp[k2*4+2]); qq.w = pk2(amp[k2*4+3]);
            *(uint4*)(po + k2*4) = qq;
        }
    }
}

extern "C" void kernel_launch(void* const* d_in, const int* in_sizes, int n_in,
                              void* d_out, int out_size, void* d_ws, size_t ws_size,
                              hipStream_t stream){
    (void)in_sizes; (void)n_in; (void)out_size; (void)ws_size;
    const float* x  = (const float*)d_in[0];
    const float* Wc = (const float*)d_in[1];
    const float* bc = (const float*)d_in[2];
    const float* Wr = (const float*)d_in[3];
    const float* br = (const float*)d_in[4];
    const float* wq = (const float*)d_in[5];
    float* ws     = (float*)d_ws;
    float* feat   = ws;
    float* qacc   = ws + 33792;
    unsigned* fincnt = (unsigned*)(ws + 33856);
    _Float16* Wh = (_Float16*)((char*)d_ws + ((size_t)1<<20));
    unsigned* SA = (unsigned*)((char*)d_ws + ((size_t)4<<20));
    unsigned* SB = SA + ((size_t)64<<16);
    float* outF = (float*)d_out;

    const int dynC = 224*72*2;           // 32256 B
    const int dynI = 65536 + 4096;       // pk + Atab/Btab
    const int dynM = 65536;              // pk
    (void)hipFuncSetAttribute(reinterpret_cast<const void*>(&k_conv_mfma),
                        hipFuncAttributeMaxDynamicSharedMemorySize, dynC);
    (void)hipFuncSetAttribute(reinterpret_cast<const void*>(&k_vqc<true,false>),
                        hipFuncAttributeMaxDynamicSharedMemorySize, dynI);
    (void)hipFuncSetAttribute(reinterpret_cast<const void*>(&k_vqc<false,false>),
                        hipFuncAttributeMaxDynamicSharedMemorySize, dynM);

    k_init0<<<128,256,0,stream>>>(Wc, Wh, ws);
    k_conv_mfma<<<64*14,512,dynC,stream>>>(x, Wh, bc, feat);
    k_vqc<true ,false><<<256,1024,dynI,stream>>>(wq, feat, Wr, br, nullptr, SA, qacc, fincnt, outF, 1);
    k_vqc<false,false><<<256,1024,dynM,stream>>>(wq, feat, Wr, br, SA, SB, qacc, fincnt, outF, 2);
    k_vqc<false,false><<<256,1024,dynM,stream>>>(wq, feat, Wr, br, SB, SA, qacc, fincnt, outF, 3);
    k_vqc<false,false><<<256,1024,dynM,stream>>>(wq, feat, Wr, br, SA, SB, qacc, fincnt, outF, 4);
    k_vqc<false,true ><<<256,1024,0,   stream>>>(wq, feat, Wr, br, SB, nullptr, qacc, fincnt, outF, 5);
}